// Round 1
// baseline (1149.421 us; speedup 1.0000x reference)
//
#include <hip/hip_runtime.h>

#define N_NODES_C 100000
#define IN_F 24
#define HID 64

// ---------------- degree / norm ----------------
__global__ void k_init_deg(float* deg, int n) {
    int i = blockIdx.x * blockDim.x + threadIdx.x;
    if (i < n) deg[i] = 1.0f;  // self-loop contributes 1
}

__global__ void k_deg_accum(const int* __restrict__ dst, float* deg, int e) {
    int i = blockIdx.x * blockDim.x + threadIdx.x;
    if (i < e) atomicAdd(&deg[dst[i]], 1.0f);
}

__global__ void k_dinv(float* deg, int n) {
    int i = blockIdx.x * blockDim.x + threadIdx.x;
    if (i < n) deg[i] = rsqrtf(deg[i]);  // deg >= 1 always (self-loop)
}

// ---------------- layer 1: h = x @ W1 ----------------
// block = 256 threads = 4 nodes x 64 out-features; W1 staged in LDS
__global__ void k_gemm1(const float* __restrict__ x, const float* __restrict__ W1,
                        float* __restrict__ h, int n) {
    __shared__ float w[IN_F * HID];
    for (int j = threadIdx.x; j < IN_F * HID; j += blockDim.x) w[j] = W1[j];
    __syncthreads();
    int t = blockIdx.x * blockDim.x + threadIdx.x;
    int node = t >> 6;
    int f = t & 63;
    if (node < n) {
        const float* xr = x + node * IN_F;
        float acc = 0.0f;
#pragma unroll
        for (int k = 0; k < IN_F; ++k) acc += xr[k] * w[k * HID + f];
        h[node * HID + f] = acc;
    }
}

// self-loop init: agg[i][f] = h[i][f] * dinv[i]^2
__global__ void k_self_init(const float* __restrict__ h, const float* __restrict__ dinv,
                            float* __restrict__ agg, int n) {
    int t = blockIdx.x * blockDim.x + threadIdx.x;
    int node = t >> 6;
    if (node < n) {
        float di = dinv[node];
        agg[t] = h[t] * di * di;
    }
}

// edge scatter for layer 1: one thread per (edge, feature)
__global__ void k_scatter1(const int* __restrict__ src, const int* __restrict__ dst,
                           const float* __restrict__ h, const float* __restrict__ dinv,
                           float* __restrict__ agg, long long total) {
    long long t = (long long)blockIdx.x * blockDim.x + threadIdx.x;
    if (t >= total) return;
    int e = (int)(t >> 6);
    int f = (int)(t & 63);
    int s = src[e];
    int d = dst[e];
    float nrm = dinv[s] * dinv[d];
    atomicAdd(&agg[(long long)d * HID + f], h[(long long)s * HID + f] * nrm);
}

// bias + relu: h1 = relu(agg + b1), written back into h buffer
__global__ void k_bias_relu(const float* __restrict__ agg, const float* __restrict__ b1,
                            float* __restrict__ h, int n) {
    int t = blockIdx.x * blockDim.x + threadIdx.x;
    int node = t >> 6;
    int f = t & 63;
    if (node < n) h[t] = fmaxf(agg[t] + b1[f], 0.0f);
}

// ---------------- layer 2 ----------------
// z[i] = h1[i] . W2 ; out[i] = b2 + z[i]*dinv[i]^2   (wave per node)
__global__ void k_z_out(const float* __restrict__ h1, const float* __restrict__ W2,
                        const float* __restrict__ b2, const float* __restrict__ dinv,
                        float* __restrict__ z, float* __restrict__ out, int n) {
    int t = blockIdx.x * blockDim.x + threadIdx.x;
    int node = t >> 6;
    int lane = t & 63;
    if (node >= n) return;
    float v = h1[(long long)node * HID + lane] * W2[lane];
#pragma unroll
    for (int off = 32; off > 0; off >>= 1) v += __shfl_down(v, off);
    if (lane == 0) {
        float di = dinv[node];
        z[node] = v;
        out[node] = b2[0] + v * di * di;
    }
}

// edge scatter for layer 2: one thread per edge
__global__ void k_scatter2(const int* __restrict__ src, const int* __restrict__ dst,
                           const float* __restrict__ z, const float* __restrict__ dinv,
                           float* __restrict__ out, int e) {
    int i = blockIdx.x * blockDim.x + threadIdx.x;
    if (i >= e) return;
    int s = src[i];
    int d = dst[i];
    atomicAdd(&out[d], z[s] * dinv[s] * dinv[d]);
}

extern "C" void kernel_launch(void* const* d_in, const int* in_sizes, int n_in,
                              void* d_out, int out_size, void* d_ws, size_t ws_size,
                              hipStream_t stream) {
    const float* x   = (const float*)d_in[0];
    const int*   ei  = (const int*)d_in[1];
    const float* W1  = (const float*)d_in[2];
    const float* b1  = (const float*)d_in[3];
    const float* W2  = (const float*)d_in[4];
    const float* b2  = (const float*)d_in[5];
    float* out = (float*)d_out;

    const int n = in_sizes[0] / IN_F;      // 100000
    const int e = in_sizes[1] / 2;         // 3200000
    const int* src = ei;
    const int* dst = ei + e;

    // workspace layout (floats): dinv[n] | h[n*64] | agg[n*64] | z[n]
    float* ws   = (float*)d_ws;
    float* dinv = ws;
    float* h    = dinv + n;
    float* agg  = h + (size_t)n * HID;
    float* z    = agg + (size_t)n * HID;

    const int B = 256;

    // degree + norm
    k_init_deg<<<(n + B - 1) / B, B, 0, stream>>>(dinv, n);
    k_deg_accum<<<(e + B - 1) / B, B, 0, stream>>>(dst, dinv, e);
    k_dinv<<<(n + B - 1) / B, B, 0, stream>>>(dinv, n);

    // layer 1
    const long long nh = (long long)n * HID;
    k_gemm1<<<(int)((nh + B - 1) / B), B, 0, stream>>>(x, W1, h, n);
    k_self_init<<<(int)((nh + B - 1) / B), B, 0, stream>>>(h, dinv, agg, n);
    const long long eh = (long long)e * HID;
    k_scatter1<<<(int)((eh + B - 1) / B), B, 0, stream>>>(src, dst, h, dinv, agg, eh);
    k_bias_relu<<<(int)((nh + B - 1) / B), B, 0, stream>>>(agg, b1, h, n);

    // layer 2
    k_z_out<<<(int)((nh + B - 1) / B), B, 0, stream>>>(h, W2, b2, dinv, z, out, n);
    k_scatter2<<<(e + B - 1) / B, B, 0, stream>>>(src, dst, z, dinv, out, e);
}

// Round 2
// 809.172 us; speedup vs baseline: 1.4205x; 1.4205x over previous
//
#include <hip/hip_runtime.h>

#define IN_F 24
#define HID 64

// ---------------- degree / norm ----------------
__global__ void k_init_deg(float* deg, int n) {
    int i = blockIdx.x * blockDim.x + threadIdx.x;
    if (i < n) deg[i] = 1.0f;  // self-loop contributes 1
}

__global__ void k_deg_accum(const int* __restrict__ dst, float* deg, int e) {
    int i = blockIdx.x * blockDim.x + threadIdx.x;
    if (i < e) atomicAdd(&deg[dst[i]], 1.0f);
}

__global__ void k_dinv(float* deg, int n) {
    int i = blockIdx.x * blockDim.x + threadIdx.x;
    if (i < n) deg[i] = rsqrtf(deg[i]);  // deg >= 1 always (self-loop)
}

// ---------------- layer 1 aggregation over RAW INPUT x (24 feats) ----------------
// self-loop init: aggX[i][k] = x[i][k] * dinv[i]^2
__global__ void k_self_init_x(const float* __restrict__ x, const float* __restrict__ dinv,
                              float* __restrict__ aggX, int n) {
    int t = blockIdx.x * blockDim.x + threadIdx.x;
    if (t >= n * IN_F) return;
    int node = t / IN_F;
    float di = dinv[node];
    aggX[t] = x[t] * di * di;
}

// edge scatter: one thread per (edge, feature<24)
__global__ void k_scatter_x(const int* __restrict__ src, const int* __restrict__ dst,
                            const float* __restrict__ x, const float* __restrict__ dinv,
                            float* __restrict__ aggX, long long total) {
    long long t = (long long)blockIdx.x * blockDim.x + threadIdx.x;
    if (t >= total) return;
    int e = (int)(t / IN_F);
    int f = (int)(t - (long long)e * IN_F);
    int s = src[e];
    int d = dst[e];
    float nrm = dinv[s] * dinv[d];
    atomicAdd(&aggX[(long long)d * IN_F + f], x[(long long)s * IN_F + f] * nrm);
}

// ---------------- dense transform + bias + relu ----------------
// h1 = relu(aggX @ W1 + b1); block = 256 = 4 nodes x 64 out-feats; W1,b1 in LDS
__global__ void k_gemm_relu(const float* __restrict__ aggX, const float* __restrict__ W1,
                            const float* __restrict__ b1, float* __restrict__ h1, int n) {
    __shared__ float w[IN_F * HID];
    __shared__ float bs[HID];
    for (int j = threadIdx.x; j < IN_F * HID; j += blockDim.x) w[j] = W1[j];
    if (threadIdx.x < HID) bs[threadIdx.x] = b1[threadIdx.x];
    __syncthreads();
    int t = blockIdx.x * blockDim.x + threadIdx.x;
    int node = t >> 6;
    int f = t & 63;
    if (node < n) {
        const float* xr = aggX + (long long)node * IN_F;
        float acc = bs[f];
#pragma unroll
        for (int k = 0; k < IN_F; ++k) acc += xr[k] * w[k * HID + f];
        h1[(long long)node * HID + f] = fmaxf(acc, 0.0f);
    }
}

// ---------------- layer 2 ----------------
// z[i] = h1[i] . W2 ; out[i] = b2 + z[i]*dinv[i]^2   (wave per node)
__global__ void k_z_out(const float* __restrict__ h1, const float* __restrict__ W2,
                        const float* __restrict__ b2, const float* __restrict__ dinv,
                        float* __restrict__ z, float* __restrict__ out, int n) {
    int t = blockIdx.x * blockDim.x + threadIdx.x;
    int node = t >> 6;
    int lane = t & 63;
    if (node >= n) return;
    float v = h1[(long long)node * HID + lane] * W2[lane];
#pragma unroll
    for (int off = 32; off > 0; off >>= 1) v += __shfl_down(v, off);
    if (lane == 0) {
        float di = dinv[node];
        z[node] = v;
        out[node] = b2[0] + v * di * di;
    }
}

// edge scatter for layer 2: one thread per edge (scalar payload)
__global__ void k_scatter2(const int* __restrict__ src, const int* __restrict__ dst,
                           const float* __restrict__ z, const float* __restrict__ dinv,
                           float* __restrict__ out, int e) {
    int i = blockIdx.x * blockDim.x + threadIdx.x;
    if (i >= e) return;
    int s = src[i];
    int d = dst[i];
    atomicAdd(&out[d], z[s] * dinv[s] * dinv[d]);
}

extern "C" void kernel_launch(void* const* d_in, const int* in_sizes, int n_in,
                              void* d_out, int out_size, void* d_ws, size_t ws_size,
                              hipStream_t stream) {
    const float* x   = (const float*)d_in[0];
    const int*   ei  = (const int*)d_in[1];
    const float* W1  = (const float*)d_in[2];
    const float* b1  = (const float*)d_in[3];
    const float* W2  = (const float*)d_in[4];
    const float* b2  = (const float*)d_in[5];
    float* out = (float*)d_out;

    const int n = in_sizes[0] / IN_F;      // 100000
    const int e = in_sizes[1] / 2;         // 3200000
    const int* src = ei;
    const int* dst = ei + e;

    // workspace layout (floats): dinv[n] | aggX[n*24] | h1[n*64] | z[n]
    float* ws   = (float*)d_ws;
    float* dinv = ws;
    float* aggX = dinv + n;
    float* h1   = aggX + (size_t)n * IN_F;
    float* z    = h1 + (size_t)n * HID;

    const int B = 256;

    // degree + norm
    k_init_deg<<<(n + B - 1) / B, B, 0, stream>>>(dinv, n);
    k_deg_accum<<<(e + B - 1) / B, B, 0, stream>>>(dst, dinv, e);
    k_dinv<<<(n + B - 1) / B, B, 0, stream>>>(dinv, n);

    // layer 1: aggregate x (24 feats), then transform
    const long long nx = (long long)n * IN_F;
    k_self_init_x<<<(int)((nx + B - 1) / B), B, 0, stream>>>(x, dinv, aggX, n);
    const long long ex = (long long)e * IN_F;
    k_scatter_x<<<(int)((ex + B - 1) / B), B, 0, stream>>>(src, dst, x, dinv, aggX, ex);
    const long long nh = (long long)n * HID;
    k_gemm_relu<<<(int)((nh + B - 1) / B), B, 0, stream>>>(aggX, W1, b1, h1, n);

    // layer 2
    k_z_out<<<(int)((nh + B - 1) / B), B, 0, stream>>>(h1, W2, b2, dinv, z, out, n);
    k_scatter2<<<(e + B - 1) / B, B, 0, stream>>>(src, dst, z, dinv, out, e);
}

// Round 3
// 715.662 us; speedup vs baseline: 1.6061x; 1.1307x over previous
//
#include <hip/hip_runtime.h>

#define IN_F 24
#define HID 64

// ---------------- zero / count / scan / fill (CSR build by dst) ----------------
__global__ void k_zero(int* p, int n) {
    int i = blockIdx.x * blockDim.x + threadIdx.x;
    if (i < n) p[i] = 0;
}

__global__ void k_count(const int* __restrict__ dst, int* __restrict__ cnt, int e) {
    int i = blockIdx.x * blockDim.x + threadIdx.x;
    if (i < e) atomicAdd(&cnt[dst[i]], 1);
}

// block-level inclusive scan (256/block)
__global__ void k_scan1(const int* __restrict__ cnt, int* __restrict__ incl,
                        int* __restrict__ partial, int n) {
    __shared__ int s[256];
    int i = blockIdx.x * 256 + threadIdx.x;
    int v = (i < n) ? cnt[i] : 0;
    s[threadIdx.x] = v;
    __syncthreads();
    for (int off = 1; off < 256; off <<= 1) {
        int t = (threadIdx.x >= (unsigned)off) ? s[threadIdx.x - off] : 0;
        __syncthreads();
        s[threadIdx.x] += t;
        __syncthreads();
    }
    if (i < n) incl[i] = s[threadIdx.x];
    if (threadIdx.x == 255) partial[blockIdx.x] = s[255];
}

// single-block exclusive scan of block partials (nb <= 512)
__global__ void k_scan2(int* __restrict__ partial, int nb) {
    __shared__ int s[512];
    int v = (threadIdx.x < (unsigned)nb) ? partial[threadIdx.x] : 0;
    s[threadIdx.x] = v;
    __syncthreads();
    for (int off = 1; off < 512; off <<= 1) {
        int t = (threadIdx.x >= (unsigned)off) ? s[threadIdx.x - off] : 0;
        __syncthreads();
        s[threadIdx.x] += t;
        __syncthreads();
    }
    if (threadIdx.x < (unsigned)nb) partial[threadIdx.x] = s[threadIdx.x] - v;  // exclusive
}

// row_start / cursor / dinv  (grid must be 256-blocked same as k_scan1)
__global__ void k_scan3(const int* __restrict__ cnt, const int* __restrict__ incl,
                        const int* __restrict__ partial, int* __restrict__ row_start,
                        int* __restrict__ cursor, float* __restrict__ dinv, int n) {
    int i = blockIdx.x * 256 + threadIdx.x;
    if (i < n) {
        int rs = incl[i] - cnt[i] + partial[blockIdx.x];
        row_start[i] = rs;
        cursor[i] = rs;
        dinv[i] = rsqrtf((float)(cnt[i] + 1));  // +1 self-loop
    }
}

__global__ void k_fill(const int* __restrict__ src, const int* __restrict__ dst,
                       int* __restrict__ cursor, int* __restrict__ csr_src, int e) {
    int i = blockIdx.x * blockDim.x + threadIdx.x;
    if (i < e) {
        int d = dst[i];
        int pos = atomicAdd(&cursor[d], 1);
        csr_src[pos] = src[i];
    }
}

// ---------------- layer 1 aggregation (gather, deterministic) ----------------
// thread = (node, f) with f in [0,32), active f<24; 24 lanes read one contiguous x-row/edge
__global__ void k_agg1(const float* __restrict__ x, const float* __restrict__ dinv,
                       const int* __restrict__ row_start, const int* __restrict__ cnt,
                       const int* __restrict__ csr_src, float* __restrict__ aggX, int n) {
    int t = blockIdx.x * blockDim.x + threadIdx.x;
    int node = t >> 5;
    int f = t & 31;
    if (node >= n || f >= IN_F) return;
    float dn = dinv[node];
    float acc = x[(long long)node * IN_F + f] * dn * dn;  // self-loop
    int row = row_start[node];
    int c = cnt[node];
    for (int j = 0; j < c; ++j) {
        int s = csr_src[row + j];
        acc += x[(long long)s * IN_F + f] * dinv[s] * dn;
    }
    aggX[(long long)node * IN_F + f] = acc;
}

// ---------------- fused: h1 = relu(aggX@W1+b1); z = h1 . W2  (wave per node) ----------------
__global__ void k_hidden_z(const float* __restrict__ aggX, const float* __restrict__ W1,
                           const float* __restrict__ b1, const float* __restrict__ W2,
                           float* __restrict__ z, int n) {
    __shared__ float w[IN_F * HID];
    __shared__ float w2s[HID];
    __shared__ float b1s[HID];
    for (int j = threadIdx.x; j < IN_F * HID; j += blockDim.x) w[j] = W1[j];
    if (threadIdx.x < HID) { w2s[threadIdx.x] = W2[threadIdx.x]; b1s[threadIdx.x] = b1[threadIdx.x]; }
    __syncthreads();
    int t = blockIdx.x * blockDim.x + threadIdx.x;
    int node = t >> 6;
    int f = t & 63;
    if (node >= n) return;
    const float* xr = aggX + (long long)node * IN_F;
    float acc = b1s[f];
#pragma unroll
    for (int k = 0; k < IN_F; ++k) acc += xr[k] * w[k * HID + f];
    float v = fmaxf(acc, 0.0f) * w2s[f];
#pragma unroll
    for (int off = 32; off > 0; off >>= 1) v += __shfl_down(v, off);
    if (f == 0) z[node] = v;
}

// ---------------- layer 2 gather: out[i] = b2 + dinv_i*(z_i*dinv_i + sum z_s*dinv_s) ----------------
__global__ void k_out(const float* __restrict__ z, const float* __restrict__ dinv,
                      const int* __restrict__ row_start, const int* __restrict__ cnt,
                      const int* __restrict__ csr_src, const float* __restrict__ b2,
                      float* __restrict__ out, int n) {
    int t = blockIdx.x * blockDim.x + threadIdx.x;
    int node = t >> 6;
    int lane = t & 63;
    if (node >= n) return;
    int row = row_start[node];
    int c = cnt[node];
    float v = 0.0f;
    for (int j = lane; j < c; j += 64) {
        int s = csr_src[row + j];
        v += z[s] * dinv[s];
    }
#pragma unroll
    for (int off = 32; off > 0; off >>= 1) v += __shfl_down(v, off);
    if (lane == 0) {
        float di = dinv[node];
        out[node] = b2[0] + di * (z[node] * di + v);
    }
}

extern "C" void kernel_launch(void* const* d_in, const int* in_sizes, int n_in,
                              void* d_out, int out_size, void* d_ws, size_t ws_size,
                              hipStream_t stream) {
    const float* x   = (const float*)d_in[0];
    const int*   ei  = (const int*)d_in[1];
    const float* W1  = (const float*)d_in[2];
    const float* b1  = (const float*)d_in[3];
    const float* W2  = (const float*)d_in[4];
    const float* b2  = (const float*)d_in[5];
    float* out = (float*)d_out;

    const int n = in_sizes[0] / IN_F;      // 100000
    const int e = in_sizes[1] / 2;         // 3200000
    const int* src = ei;
    const int* dst = ei + e;

    const int B = 256;
    const int nb = (n + B - 1) / B;        // 391 <= 512

    // workspace layout: ints first, then floats
    int* cnt       = (int*)d_ws;
    int* incl      = cnt + n;
    int* partial   = incl + n;             // 512 entries
    int* row_start = partial + 512;
    int* cursor    = row_start + n;
    int* csr_src   = cursor + n;           // e entries
    float* dinv    = (float*)(csr_src + e);
    float* aggX    = dinv + n;             // n*24
    float* z       = aggX + (size_t)n * IN_F;

    // CSR build
    k_zero<<<nb, B, 0, stream>>>(cnt, n);
    k_count<<<(e + B - 1) / B, B, 0, stream>>>(dst, cnt, e);
    k_scan1<<<nb, B, 0, stream>>>(cnt, incl, partial, n);
    k_scan2<<<1, 512, 0, stream>>>(partial, nb);
    k_scan3<<<nb, B, 0, stream>>>(cnt, incl, partial, row_start, cursor, dinv, n);
    k_fill<<<(e + B - 1) / B, B, 0, stream>>>(src, dst, cursor, csr_src, e);

    // layer 1: gather-aggregate x, then fused transform + z
    const long long n32 = (long long)n * 32;
    k_agg1<<<(int)((n32 + B - 1) / B), B, 0, stream>>>(x, dinv, row_start, cnt, csr_src, aggX, n);
    const long long n64 = (long long)n * 64;
    k_hidden_z<<<(int)((n64 + B - 1) / B), B, 0, stream>>>(aggX, W1, b1, W2, z, n);

    // layer 2: gather z
    k_out<<<(int)((n64 + B - 1) / B), B, 0, stream>>>(z, dinv, row_start, cnt, csr_src, b2, out, n);
}

// Round 4
// 523.007 us; speedup vs baseline: 2.1977x; 1.3684x over previous
//
#include <hip/hip_runtime.h>

#define IN_F 24
#define HID 64

// ---------------- zero / count+rank / scan / fill (CSR build by dst) ----------------
__global__ void k_zero(int* p, int n) {
    int i = blockIdx.x * blockDim.x + threadIdx.x;
    if (i < n) p[i] = 0;
}

// count degree AND record each edge's rank within its dst row (atomic return value)
__global__ void k_count(const int* __restrict__ dst, int* __restrict__ cnt,
                        int* __restrict__ rank, int e) {
    int i = blockIdx.x * blockDim.x + threadIdx.x;
    if (i < e) rank[i] = atomicAdd(&cnt[dst[i]], 1);
}

// block-level inclusive scan (256/block)
__global__ void k_scan1(const int* __restrict__ cnt, int* __restrict__ incl,
                        int* __restrict__ partial, int n) {
    __shared__ int s[256];
    int i = blockIdx.x * 256 + threadIdx.x;
    int v = (i < n) ? cnt[i] : 0;
    s[threadIdx.x] = v;
    __syncthreads();
    for (int off = 1; off < 256; off <<= 1) {
        int t = (threadIdx.x >= (unsigned)off) ? s[threadIdx.x - off] : 0;
        __syncthreads();
        s[threadIdx.x] += t;
        __syncthreads();
    }
    if (i < n) incl[i] = s[threadIdx.x];
    if (threadIdx.x == 255) partial[blockIdx.x] = s[255];
}

// single-block exclusive scan of block partials (nb <= 512)
__global__ void k_scan2(int* __restrict__ partial, int nb) {
    __shared__ int s[512];
    int v = (threadIdx.x < (unsigned)nb) ? partial[threadIdx.x] : 0;
    s[threadIdx.x] = v;
    __syncthreads();
    for (int off = 1; off < 512; off <<= 1) {
        int t = (threadIdx.x >= (unsigned)off) ? s[threadIdx.x - off] : 0;
        __syncthreads();
        s[threadIdx.x] += t;
        __syncthreads();
    }
    if (threadIdx.x < (unsigned)nb) partial[threadIdx.x] = s[threadIdx.x] - v;  // exclusive
}

// row_start / dinv  (grid must be 256-blocked same as k_scan1)
__global__ void k_scan3(const int* __restrict__ cnt, const int* __restrict__ incl,
                        const int* __restrict__ partial, int* __restrict__ row_start,
                        float* __restrict__ dinv, int n) {
    int i = blockIdx.x * 256 + threadIdx.x;
    if (i < n) {
        row_start[i] = incl[i] - cnt[i] + partial[blockIdx.x];
        dinv[i] = rsqrtf((float)(cnt[i] + 1));  // +1 self-loop
    }
}

// XCD-partitioned, atomic-free fill.
// blockIdx%8 -> dst-range (presumed XCD via round-robin dispatch); blockIdx/8 -> edge slice.
// Each group's csr lines are dirtied by one L2 only and written back ~once.
__global__ void k_fill_part(const int* __restrict__ src, const int* __restrict__ dst,
                            const int* __restrict__ rank, const int* __restrict__ row_start,
                            int* __restrict__ csr_src, int e, int n) {
    int group = blockIdx.x & 7;
    int sub   = blockIdx.x >> 3;
    int nsub  = gridDim.x >> 3;
    int lo = (int)((long long)n * group >> 3);
    int hi = (int)((long long)n * (group + 1) >> 3);
    long long begin = (long long)e * sub / nsub;
    long long end   = (long long)e * (sub + 1) / nsub;
    for (long long i = begin + threadIdx.x; i < end; i += blockDim.x) {
        int d = dst[i];
        if (d >= lo && d < hi) {
            csr_src[row_start[d] + rank[i]] = src[i];
        }
    }
}

// ---------------- layer 1 aggregation (gather, deterministic) ----------------
// thread = (node, f) with f in [0,32), active f<24; 24 lanes read one contiguous x-row/edge
__global__ void k_agg1(const float* __restrict__ x, const float* __restrict__ dinv,
                       const int* __restrict__ row_start, const int* __restrict__ cnt,
                       const int* __restrict__ csr_src, float* __restrict__ aggX, int n) {
    int t = blockIdx.x * blockDim.x + threadIdx.x;
    int node = t >> 5;
    int f = t & 31;
    if (node >= n || f >= IN_F) return;
    float dn = dinv[node];
    float acc = x[(long long)node * IN_F + f] * dn * dn;  // self-loop
    int row = row_start[node];
    int c = cnt[node];
    for (int j = 0; j < c; ++j) {
        int s = csr_src[row + j];
        acc += x[(long long)s * IN_F + f] * dinv[s] * dn;
    }
    aggX[(long long)node * IN_F + f] = acc;
}

// ---------------- fused: h1 = relu(aggX@W1+b1); z = h1 . W2  (wave per node) ----------------
__global__ void k_hidden_z(const float* __restrict__ aggX, const float* __restrict__ W1,
                           const float* __restrict__ b1, const float* __restrict__ W2,
                           float* __restrict__ z, int n) {
    __shared__ float w[IN_F * HID];
    __shared__ float w2s[HID];
    __shared__ float b1s[HID];
    for (int j = threadIdx.x; j < IN_F * HID; j += blockDim.x) w[j] = W1[j];
    if (threadIdx.x < HID) { w2s[threadIdx.x] = W2[threadIdx.x]; b1s[threadIdx.x] = b1[threadIdx.x]; }
    __syncthreads();
    int t = blockIdx.x * blockDim.x + threadIdx.x;
    int node = t >> 6;
    int f = t & 63;
    if (node >= n) return;
    const float* xr = aggX + (long long)node * IN_F;
    float acc = b1s[f];
#pragma unroll
    for (int k = 0; k < IN_F; ++k) acc += xr[k] * w[k * HID + f];
    float v = fmaxf(acc, 0.0f) * w2s[f];
#pragma unroll
    for (int off = 32; off > 0; off >>= 1) v += __shfl_down(v, off);
    if (f == 0) z[node] = v;
}

// ---------------- layer 2 gather: out[i] = b2 + dinv_i*(z_i*dinv_i + sum z_s*dinv_s) ----------------
__global__ void k_out(const float* __restrict__ z, const float* __restrict__ dinv,
                      const int* __restrict__ row_start, const int* __restrict__ cnt,
                      const int* __restrict__ csr_src, const float* __restrict__ b2,
                      float* __restrict__ out, int n) {
    int t = blockIdx.x * blockDim.x + threadIdx.x;
    int node = t >> 6;
    int lane = t & 63;
    if (node >= n) return;
    int row = row_start[node];
    int c = cnt[node];
    float v = 0.0f;
    for (int j = lane; j < c; j += 64) {
        int s = csr_src[row + j];
        v += z[s] * dinv[s];
    }
#pragma unroll
    for (int off = 32; off > 0; off >>= 1) v += __shfl_down(v, off);
    if (lane == 0) {
        float di = dinv[node];
        out[node] = b2[0] + di * (z[node] * di + v);
    }
}

extern "C" void kernel_launch(void* const* d_in, const int* in_sizes, int n_in,
                              void* d_out, int out_size, void* d_ws, size_t ws_size,
                              hipStream_t stream) {
    const float* x   = (const float*)d_in[0];
    const int*   ei  = (const int*)d_in[1];
    const float* W1  = (const float*)d_in[2];
    const float* b1  = (const float*)d_in[3];
    const float* W2  = (const float*)d_in[4];
    const float* b2  = (const float*)d_in[5];
    float* out = (float*)d_out;

    const int n = in_sizes[0] / IN_F;      // 100000
    const int e = in_sizes[1] / 2;         // 3200000
    const int* src = ei;
    const int* dst = ei + e;

    const int B = 256;
    const int nb = (n + B - 1) / B;        // 391 <= 512

    // workspace layout: ints first, then floats
    int* cnt       = (int*)d_ws;
    int* incl      = cnt + n;
    int* partial   = incl + n;             // 512 entries
    int* row_start = partial + 512;
    int* rank      = row_start + n;        // e entries
    int* csr_src   = rank + e;             // e entries
    float* dinv    = (float*)(csr_src + e);
    float* aggX    = dinv + n;             // n*24
    float* z       = aggX + (size_t)n * IN_F;

    // CSR build
    k_zero<<<nb, B, 0, stream>>>(cnt, n);
    k_count<<<(e + B - 1) / B, B, 0, stream>>>(dst, cnt, rank, e);
    k_scan1<<<nb, B, 0, stream>>>(cnt, incl, partial, n);
    k_scan2<<<1, 512, 0, stream>>>(partial, nb);
    k_scan3<<<nb, B, 0, stream>>>(cnt, incl, partial, row_start, dinv, n);
    k_fill_part<<<2048, B, 0, stream>>>(src, dst, rank, row_start, csr_src, e, n);

    // layer 1: gather-aggregate x, then fused transform + z
    const long long n32 = (long long)n * 32;
    k_agg1<<<(int)((n32 + B - 1) / B), B, 0, stream>>>(x, dinv, row_start, cnt, csr_src, aggX, n);
    const long long n64 = (long long)n * 64;
    k_hidden_z<<<(int)((n64 + B - 1) / B), B, 0, stream>>>(aggX, W1, b1, W2, z, n);

    // layer 2: gather z
    k_out<<<(int)((n64 + B - 1) / B), B, 0, stream>>>(z, dinv, row_start, cnt, csr_src, b2, out, n);
}

// Round 5
// 506.937 us; speedup vs baseline: 2.2674x; 1.0317x over previous
//
#include <hip/hip_runtime.h>
#include <hip/hip_fp16.h>

#define IN_F 24
#define HID 64

// ---------------- zero / count+rank / scan / fill (CSR build by dst) ----------------
__global__ void k_zero(int* p, int n) {
    int i = blockIdx.x * blockDim.x + threadIdx.x;
    if (i < n) p[i] = 0;
}

// count degree AND record each edge's rank within its dst row (atomic return value)
__global__ void k_count(const int* __restrict__ dst, int* __restrict__ cnt,
                        int* __restrict__ rank, int e) {
    int i = blockIdx.x * blockDim.x + threadIdx.x;
    if (i < e) rank[i] = atomicAdd(&cnt[dst[i]], 1);
}

// block-level inclusive scan (256/block)
__global__ void k_scan1(const int* __restrict__ cnt, int* __restrict__ incl,
                        int* __restrict__ partial, int n) {
    __shared__ int s[256];
    int i = blockIdx.x * 256 + threadIdx.x;
    int v = (i < n) ? cnt[i] : 0;
    s[threadIdx.x] = v;
    __syncthreads();
    for (int off = 1; off < 256; off <<= 1) {
        int t = (threadIdx.x >= (unsigned)off) ? s[threadIdx.x - off] : 0;
        __syncthreads();
        s[threadIdx.x] += t;
        __syncthreads();
    }
    if (i < n) incl[i] = s[threadIdx.x];
    if (threadIdx.x == 255) partial[blockIdx.x] = s[255];
}

// single-block exclusive scan of block partials (nb <= 512)
__global__ void k_scan2(int* __restrict__ partial, int nb) {
    __shared__ int s[512];
    int v = (threadIdx.x < (unsigned)nb) ? partial[threadIdx.x] : 0;
    s[threadIdx.x] = v;
    __syncthreads();
    for (int off = 1; off < 512; off <<= 1) {
        int t = (threadIdx.x >= (unsigned)off) ? s[threadIdx.x - off] : 0;
        __syncthreads();
        s[threadIdx.x] += t;
        __syncthreads();
    }
    if (threadIdx.x < (unsigned)nb) partial[threadIdx.x] = s[threadIdx.x] - v;  // exclusive
}

// row_start / dinv  (grid must be 256-blocked same as k_scan1)
__global__ void k_scan3(const int* __restrict__ cnt, const int* __restrict__ incl,
                        const int* __restrict__ partial, int* __restrict__ row_start,
                        float* __restrict__ dinv, int n) {
    int i = blockIdx.x * 256 + threadIdx.x;
    if (i < n) {
        row_start[i] = incl[i] - cnt[i] + partial[blockIdx.x];
        dinv[i] = rsqrtf((float)(cnt[i] + 1));  // +1 self-loop
    }
}

// pack pre-scaled source features: xs[i][f] = f16(x[i][f] * dinv[i])  (48 B rows, 4.8 MB)
__global__ void k_pack(const float* __restrict__ x, const float* __restrict__ dinv,
                       __half* __restrict__ xs, int n) {
    int t = blockIdx.x * blockDim.x + threadIdx.x;
    int node = t >> 5;
    int f = t & 31;
    if (node >= n || f >= IN_F) return;
    xs[(long long)node * IN_F + f] = __float2half(x[(long long)node * IN_F + f] * dinv[node]);
}

// XCD-partitioned, atomic-free fill.
// blockIdx%8 -> dst-range (presumed XCD via round-robin dispatch); blockIdx/8 -> edge slice.
__global__ void k_fill_part(const int* __restrict__ src, const int* __restrict__ dst,
                            const int* __restrict__ rank, const int* __restrict__ row_start,
                            int* __restrict__ csr_src, int e, int n) {
    int group = blockIdx.x & 7;
    int sub   = blockIdx.x >> 3;
    int nsub  = gridDim.x >> 3;
    int lo = (int)((long long)n * group >> 3);
    int hi = (int)((long long)n * (group + 1) >> 3);
    long long begin = (long long)e * sub / nsub;
    long long end   = (long long)e * (sub + 1) / nsub;
    for (long long i = begin + threadIdx.x; i < end; i += blockDim.x) {
        int d = dst[i];
        if (d >= lo && d < hi) {
            csr_src[row_start[d] + rank[i]] = src[i];
        }
    }
}

// ---------------- layer 1 aggregation (gather, f16 pre-scaled payload) ----------------
// thread = (node, f) with f in [0,32), active f<24; 24 lanes read a contiguous 48 B row/edge
__global__ void k_agg1(const float* __restrict__ x, const __half* __restrict__ xs,
                       const float* __restrict__ dinv, const int* __restrict__ row_start,
                       const int* __restrict__ cnt, const int* __restrict__ csr_src,
                       float* __restrict__ aggX, int n) {
    int t = blockIdx.x * blockDim.x + threadIdx.x;
    int node = t >> 5;
    int f = t & 31;
    if (node >= n || f >= IN_F) return;
    float dn = dinv[node];
    float acc = x[(long long)node * IN_F + f] * dn;  // self-loop (x * dinv; one more dn below)
    int row = row_start[node];
    int c = cnt[node];
    for (int j = 0; j < c; ++j) {
        int s = csr_src[row + j];
        acc += __half2float(xs[(long long)s * IN_F + f]);
    }
    aggX[(long long)node * IN_F + f] = acc * dn;
}

// ---------------- fused: h1 = relu(aggX@W1+b1); zs = (h1 . W2) * dinv  (wave per node) ----------------
__global__ void k_hidden_z(const float* __restrict__ aggX, const float* __restrict__ W1,
                           const float* __restrict__ b1, const float* __restrict__ W2,
                           const float* __restrict__ dinv, float* __restrict__ zs, int n) {
    __shared__ float w[IN_F * HID];
    __shared__ float w2s[HID];
    __shared__ float b1s[HID];
    for (int j = threadIdx.x; j < IN_F * HID; j += blockDim.x) w[j] = W1[j];
    if (threadIdx.x < HID) { w2s[threadIdx.x] = W2[threadIdx.x]; b1s[threadIdx.x] = b1[threadIdx.x]; }
    __syncthreads();
    int t = blockIdx.x * blockDim.x + threadIdx.x;
    int node = t >> 6;
    int f = t & 63;
    if (node >= n) return;
    const float* xr = aggX + (long long)node * IN_F;
    float acc = b1s[f];
#pragma unroll
    for (int k = 0; k < IN_F; ++k) acc += xr[k] * w[k * HID + f];
    float v = fmaxf(acc, 0.0f) * w2s[f];
#pragma unroll
    for (int off = 32; off > 0; off >>= 1) v += __shfl_down(v, off);
    if (f == 0) zs[node] = v * dinv[node];
}

// ---------------- layer 2 gather: out[i] = b2 + dinv_i*(zs_i + sum zs_s) ----------------
__global__ void k_out(const float* __restrict__ zs, const float* __restrict__ dinv,
                      const int* __restrict__ row_start, const int* __restrict__ cnt,
                      const int* __restrict__ csr_src, const float* __restrict__ b2,
                      float* __restrict__ out, int n) {
    int t = blockIdx.x * blockDim.x + threadIdx.x;
    int node = t >> 6;
    int lane = t & 63;
    if (node >= n) return;
    int row = row_start[node];
    int c = cnt[node];
    float v = 0.0f;
    for (int j = lane; j < c; j += 64) {
        v += zs[csr_src[row + j]];
    }
#pragma unroll
    for (int off = 32; off > 0; off >>= 1) v += __shfl_down(v, off);
    if (lane == 0) {
        out[node] = b2[0] + dinv[node] * (zs[node] + v);
    }
}

extern "C" void kernel_launch(void* const* d_in, const int* in_sizes, int n_in,
                              void* d_out, int out_size, void* d_ws, size_t ws_size,
                              hipStream_t stream) {
    const float* x   = (const float*)d_in[0];
    const int*   ei  = (const int*)d_in[1];
    const float* W1  = (const float*)d_in[2];
    const float* b1  = (const float*)d_in[3];
    const float* W2  = (const float*)d_in[4];
    const float* b2  = (const float*)d_in[5];
    float* out = (float*)d_out;

    const int n = in_sizes[0] / IN_F;      // 100000
    const int e = in_sizes[1] / 2;         // 3200000
    const int* src = ei;
    const int* dst = ei + e;

    const int B = 256;
    const int nb = (n + B - 1) / B;        // 391 <= 512

    // workspace layout: ints first, then floats, then halves
    int* cnt       = (int*)d_ws;
    int* incl      = cnt + n;
    int* partial   = incl + n;             // 512 entries
    int* row_start = partial + 512;
    int* rank      = row_start + n;        // e entries
    int* csr_src   = rank + e;             // e entries
    float* dinv    = (float*)(csr_src + e);
    float* aggX    = dinv + n;             // n*24
    float* zs      = aggX + (size_t)n * IN_F;
    __half* xs     = (__half*)(zs + n);    // n*24 halves

    // CSR build
    k_zero<<<nb, B, 0, stream>>>(cnt, n);
    k_count<<<(e + B - 1) / B, B, 0, stream>>>(dst, cnt, rank, e);
    k_scan1<<<nb, B, 0, stream>>>(cnt, incl, partial, n);
    k_scan2<<<1, 512, 0, stream>>>(partial, nb);
    k_scan3<<<nb, B, 0, stream>>>(cnt, incl, partial, row_start, dinv, n);
    k_fill_part<<<2048, B, 0, stream>>>(src, dst, rank, row_start, csr_src, e, n);

    // pack pre-scaled f16 features (needs dinv)
    const long long n32 = (long long)n * 32;
    k_pack<<<(int)((n32 + B - 1) / B), B, 0, stream>>>(x, dinv, xs, n);

    // layer 1: gather-aggregate xs, then fused transform + zs
    k_agg1<<<(int)((n32 + B - 1) / B), B, 0, stream>>>(x, xs, dinv, row_start, cnt, csr_src, aggX, n);
    const long long n64 = (long long)n * 64;
    k_hidden_z<<<(int)((n64 + B - 1) / B), B, 0, stream>>>(aggX, W1, b1, W2, dinv, zs, n);

    // layer 2: gather zs
    k_out<<<(int)((n64 + B - 1) / B), B, 0, stream>>>(zs, dinv, row_start, cnt, csr_src, b2, out, n);
}

// Round 6
// 410.538 us; speedup vs baseline: 2.7998x; 1.2348x over previous
//
#include <hip/hip_runtime.h>
#include <hip/hip_fp16.h>

#define IN_F 24
#define HID 64

// ---------------- zero / count+rank / scan / fill (CSR build by dst) ----------------
__global__ void k_zero(int* p, int n) {
    int i = blockIdx.x * blockDim.x + threadIdx.x;
    if (i < n) p[i] = 0;
}

// count degree AND record each edge's rank within its dst row (atomic return value)
__global__ void k_count(const int* __restrict__ dst, int* __restrict__ cnt,
                        int* __restrict__ rank, int e) {
    int i = blockIdx.x * blockDim.x + threadIdx.x;
    if (i < e) rank[i] = atomicAdd(&cnt[dst[i]], 1);
}

// block-level inclusive scan (256/block)
__global__ void k_scan1(const int* __restrict__ cnt, int* __restrict__ incl,
                        int* __restrict__ partial, int n) {
    __shared__ int s[256];
    int i = blockIdx.x * 256 + threadIdx.x;
    int v = (i < n) ? cnt[i] : 0;
    s[threadIdx.x] = v;
    __syncthreads();
    for (int off = 1; off < 256; off <<= 1) {
        int t = (threadIdx.x >= (unsigned)off) ? s[threadIdx.x - off] : 0;
        __syncthreads();
        s[threadIdx.x] += t;
        __syncthreads();
    }
    if (i < n) incl[i] = s[threadIdx.x];
    if (threadIdx.x == 255) partial[blockIdx.x] = s[255];
}

// single-block exclusive scan of block partials (nb <= 512)
__global__ void k_scan2(int* __restrict__ partial, int nb) {
    __shared__ int s[512];
    int v = (threadIdx.x < (unsigned)nb) ? partial[threadIdx.x] : 0;
    s[threadIdx.x] = v;
    __syncthreads();
    for (int off = 1; off < 512; off <<= 1) {
        int t = (threadIdx.x >= (unsigned)off) ? s[threadIdx.x - off] : 0;
        __syncthreads();
        s[threadIdx.x] += t;
        __syncthreads();
    }
    if (threadIdx.x < (unsigned)nb) partial[threadIdx.x] = s[threadIdx.x] - v;  // exclusive
}

// row_start / dinv  (grid must be 256-blocked same as k_scan1)
__global__ void k_scan3(const int* __restrict__ cnt, const int* __restrict__ incl,
                        const int* __restrict__ partial, int* __restrict__ row_start,
                        float* __restrict__ dinv, int n) {
    int i = blockIdx.x * 256 + threadIdx.x;
    if (i < n) {
        row_start[i] = incl[i] - cnt[i] + partial[blockIdx.x];
        dinv[i] = rsqrtf((float)(cnt[i] + 1));  // +1 self-loop
    }
}

// pack pre-scaled source features: xs[i][f] = f16(x[i][f] * dinv[i])  (48 B rows, 4.8 MB)
__global__ void k_pack(const float* __restrict__ x, const float* __restrict__ dinv,
                       __half* __restrict__ xs, int n) {
    int t = blockIdx.x * blockDim.x + threadIdx.x;
    int node = t >> 5;
    int f = t & 31;
    if (node >= n || f >= IN_F) return;
    xs[(long long)node * IN_F + f] = __float2half(x[(long long)node * IN_F + f] * dinv[node]);
}

// XCD-partitioned, atomic-free fill.
__global__ void k_fill_part(const int* __restrict__ src, const int* __restrict__ dst,
                            const int* __restrict__ rank, const int* __restrict__ row_start,
                            int* __restrict__ csr_src, int e, int n) {
    int group = blockIdx.x & 7;
    int sub   = blockIdx.x >> 3;
    int nsub  = gridDim.x >> 3;
    int lo = (int)((long long)n * group >> 3);
    int hi = (int)((long long)n * (group + 1) >> 3);
    long long begin = (long long)e * sub / nsub;
    long long end   = (long long)e * (sub + 1) / nsub;
    for (long long i = begin + threadIdx.x; i < end; i += blockDim.x) {
        int d = dst[i];
        if (d >= lo && d < hi) {
            csr_src[row_start[d] + rank[i]] = src[i];
        }
    }
}

// ---------------- layer 1 aggregation: 16-lane group per node, half2 payload, unroll-8 ----------------
// 12 active lanes/node each load one half2 (4 B) of the 48 B row; 8 edges in flight per group.
__global__ void k_agg1(const float* __restrict__ x, const __half2* __restrict__ xs2,
                       const float* __restrict__ dinv, const int* __restrict__ row_start,
                       const int* __restrict__ cnt, const int* __restrict__ csr_src,
                       float2* __restrict__ aggX2, int n) {
    int t = blockIdx.x * blockDim.x + threadIdx.x;
    int node = t >> 4;
    int f2 = t & 15;
    if (node >= n || f2 >= 12) return;
    int row = row_start[node];
    int c = cnt[node];
    float ax = 0.0f, ay = 0.0f;
    int j = 0;
    for (; j + 8 <= c; j += 8) {
        const int* cp = csr_src + row + j;
        int s0 = cp[0], s1 = cp[1], s2 = cp[2], s3 = cp[3];
        int s4 = cp[4], s5 = cp[5], s6 = cp[6], s7 = cp[7];
        __half2 h0 = xs2[s0 * 12 + f2];
        __half2 h1 = xs2[s1 * 12 + f2];
        __half2 h2 = xs2[s2 * 12 + f2];
        __half2 h3 = xs2[s3 * 12 + f2];
        __half2 h4 = xs2[s4 * 12 + f2];
        __half2 h5 = xs2[s5 * 12 + f2];
        __half2 h6 = xs2[s6 * 12 + f2];
        __half2 h7 = xs2[s7 * 12 + f2];
        float2 f0 = __half22float2(h0), f1 = __half22float2(h1);
        float2 f2v = __half22float2(h2), f3 = __half22float2(h3);
        float2 f4 = __half22float2(h4), f5 = __half22float2(h5);
        float2 f6 = __half22float2(h6), f7 = __half22float2(h7);
        ax += (f0.x + f1.x) + (f2v.x + f3.x) + ((f4.x + f5.x) + (f6.x + f7.x));
        ay += (f0.y + f1.y) + (f2v.y + f3.y) + ((f4.y + f5.y) + (f6.y + f7.y));
    }
    for (; j < c; ++j) {
        int s = csr_src[row + j];
        float2 fv = __half22float2(xs2[s * 12 + f2]);
        ax += fv.x;
        ay += fv.y;
    }
    float dn = dinv[node];
    // self-loop: x * dinv^2 (keep full f32)
    float sx = x[(long long)node * IN_F + 2 * f2];
    float sy = x[(long long)node * IN_F + 2 * f2 + 1];
    float2 outv;
    outv.x = (ax + sx * dn) * dn;
    outv.y = (ay + sy * dn) * dn;
    aggX2[(long long)node * 12 + f2] = outv;
}

// ---------------- fused: h1 = relu(aggX@W1+b1); zs = (h1 . W2) * dinv  (wave per node) ----------------
__global__ void k_hidden_z(const float* __restrict__ aggX, const float* __restrict__ W1,
                           const float* __restrict__ b1, const float* __restrict__ W2,
                           const float* __restrict__ dinv, float* __restrict__ zs, int n) {
    __shared__ float w[IN_F * HID];
    __shared__ float w2s[HID];
    __shared__ float b1s[HID];
    for (int j = threadIdx.x; j < IN_F * HID; j += blockDim.x) w[j] = W1[j];
    if (threadIdx.x < HID) { w2s[threadIdx.x] = W2[threadIdx.x]; b1s[threadIdx.x] = b1[threadIdx.x]; }
    __syncthreads();
    int t = blockIdx.x * blockDim.x + threadIdx.x;
    int node = t >> 6;
    int f = t & 63;
    if (node >= n) return;
    const float* xr = aggX + (long long)node * IN_F;
    float acc = b1s[f];
#pragma unroll
    for (int k = 0; k < IN_F; ++k) acc += xr[k] * w[k * HID + f];
    float v = fmaxf(acc, 0.0f) * w2s[f];
#pragma unroll
    for (int off = 32; off > 0; off >>= 1) v += __shfl_down(v, off);
    if (f == 0) zs[node] = v * dinv[node];
}

// ---------------- layer 2 gather: out[i] = b2 + dinv_i*(zs_i + sum zs_s) ----------------
__global__ void k_out(const float* __restrict__ zs, const float* __restrict__ dinv,
                      const int* __restrict__ row_start, const int* __restrict__ cnt,
                      const int* __restrict__ csr_src, const float* __restrict__ b2,
                      float* __restrict__ out, int n) {
    int t = blockIdx.x * blockDim.x + threadIdx.x;
    int node = t >> 6;
    int lane = t & 63;
    if (node >= n) return;
    int row = row_start[node];
    int c = cnt[node];
    float v = 0.0f;
    for (int j = lane; j < c; j += 64) {
        v += zs[csr_src[row + j]];
    }
#pragma unroll
    for (int off = 32; off > 0; off >>= 1) v += __shfl_down(v, off);
    if (lane == 0) {
        out[node] = b2[0] + dinv[node] * (zs[node] + v);
    }
}

extern "C" void kernel_launch(void* const* d_in, const int* in_sizes, int n_in,
                              void* d_out, int out_size, void* d_ws, size_t ws_size,
                              hipStream_t stream) {
    const float* x   = (const float*)d_in[0];
    const int*   ei  = (const int*)d_in[1];
    const float* W1  = (const float*)d_in[2];
    const float* b1  = (const float*)d_in[3];
    const float* W2  = (const float*)d_in[4];
    const float* b2  = (const float*)d_in[5];
    float* out = (float*)d_out;

    const int n = in_sizes[0] / IN_F;      // 100000
    const int e = in_sizes[1] / 2;         // 3200000
    const int* src = ei;
    const int* dst = ei + e;

    const int B = 256;
    const int nb = (n + B - 1) / B;        // 391 <= 512

    // workspace layout: ints first, then floats, then halves (all offsets 8-B aligned: n,e even)
    int* cnt       = (int*)d_ws;
    int* incl      = cnt + n;
    int* partial   = incl + n;             // 512 entries
    int* row_start = partial + 512;
    int* rank      = row_start + n;        // e entries
    int* csr_src   = rank + e;             // e entries
    float* dinv    = (float*)(csr_src + e);
    float* aggX    = dinv + n;             // n*24
    float* zs      = aggX + (size_t)n * IN_F;
    __half* xs     = (__half*)(zs + n);    // n*24 halves

    // CSR build
    k_zero<<<nb, B, 0, stream>>>(cnt, n);
    k_count<<<(e + B - 1) / B, B, 0, stream>>>(dst, cnt, rank, e);
    k_scan1<<<nb, B, 0, stream>>>(cnt, incl, partial, n);
    k_scan2<<<1, 512, 0, stream>>>(partial, nb);
    k_scan3<<<nb, B, 0, stream>>>(cnt, incl, partial, row_start, dinv, n);
    k_fill_part<<<2048, B, 0, stream>>>(src, dst, rank, row_start, csr_src, e, n);

    // pack pre-scaled f16 features (needs dinv)
    const long long n32 = (long long)n * 32;
    k_pack<<<(int)((n32 + B - 1) / B), B, 0, stream>>>(x, dinv, xs, n);

    // layer 1: gather-aggregate xs (16 lanes/node), then fused transform + zs
    const long long n16 = (long long)n * 16;
    k_agg1<<<(int)((n16 + B - 1) / B), B, 0, stream>>>(x, (const __half2*)xs, dinv,
                                                      row_start, cnt, csr_src,
                                                      (float2*)aggX, n);
    const long long n64 = (long long)n * 64;
    k_hidden_z<<<(int)((n64 + B - 1) / B), B, 0, stream>>>(aggX, W1, b1, W2, dinv, zs, n);

    // layer 2: gather zs
    k_out<<<(int)((n64 + B - 1) / B), B, 0, stream>>>(zs, dinv, row_start, cnt, csr_src, b2, out, n);
}

// Round 7
// 301.321 us; speedup vs baseline: 3.8146x; 1.3625x over previous
//
#include <hip/hip_runtime.h>
#include <hip/hip_fp16.h>

#define IN_F 24
#define HID 64
#define NG 8        // dst groups (XCD-partitioned)
#define NSUB 64     // edge slices per group
#define GMAX 12512  // max nodes per group (LDS histogram entries)

typedef unsigned short u16;
typedef unsigned int u32;

// ---------------- CSR build, atomic-free (LDS histograms) ----------------
// Pass A: per-(group, slice) histogram of dst into LDS, dumped as u16.
__global__ __launch_bounds__(256) void k_hist(const int* __restrict__ dst,
                                              u16* __restrict__ hb, int e, int n) {
    __shared__ u32 h[GMAX];
    int g = blockIdx.x & (NG - 1);
    int sub = blockIdx.x >> 3;
    int lo = (int)((long long)n * g / NG);
    int hi = (int)((long long)n * (g + 1) / NG);
    int gsz = hi - lo;
    for (int j = threadIdx.x; j < gsz; j += 256) h[j] = 0;
    __syncthreads();
    long long begin = (long long)e * sub / NSUB;
    long long end   = (long long)e * (sub + 1) / NSUB;
    long long b4 = begin + ((4 - (begin & 3)) & 3);
    if (b4 > end) b4 = end;
    long long e4 = b4 + ((end - b4) & ~3LL);
    for (long long i = begin + threadIdx.x; i < b4; i += 256) {
        int d = dst[i];
        if (d >= lo && d < hi) atomicAdd(&h[d - lo], 1u);
    }
    const int4* dp = (const int4*)(dst + b4);
    long long nv = (e4 - b4) >> 2;
    for (long long it = threadIdx.x; it < nv; it += 256) {
        int4 v = dp[it];
        if (v.x >= lo && v.x < hi) atomicAdd(&h[v.x - lo], 1u);
        if (v.y >= lo && v.y < hi) atomicAdd(&h[v.y - lo], 1u);
        if (v.z >= lo && v.z < hi) atomicAdd(&h[v.z - lo], 1u);
        if (v.w >= lo && v.w < hi) atomicAdd(&h[v.w - lo], 1u);
    }
    for (long long i = e4 + threadIdx.x; i < end; i += 256) {
        int d = dst[i];
        if (d >= lo && d < hi) atomicAdd(&h[d - lo], 1u);
    }
    __syncthreads();
    u16* outp = hb + (size_t)(g * NSUB + sub) * GMAX;
    for (int j = threadIdx.x; j < gsz; j += 256) outp[j] = (u16)h[j];
}

// Pass B: per node, exclusive prefix over the NSUB counts IN PLACE; total -> cnt.
__global__ void k_boff(u16* __restrict__ hb, int* __restrict__ cnt, int n) {
    int i = blockIdx.x * blockDim.x + threadIdx.x;
    if (i >= n) return;
    int g = (int)(((long long)i * NG) / n);
    while (i >= (int)((long long)n * (g + 1) / NG)) g++;
    while (i < (int)((long long)n * g / NG)) g--;
    int lo = (int)((long long)n * g / NG);
    int j = i - lo;
    u16* p = hb + (size_t)(g * NSUB) * GMAX + j;
    u32 run = 0;
    for (int s = 0; s < NSUB; ++s) {
        u32 v = p[(size_t)s * GMAX];
        p[(size_t)s * GMAX] = (u16)run;
        run += v;
    }
    cnt[i] = (int)run;
}

// block-level inclusive scan (256/block)
__global__ void k_scan1(const int* __restrict__ cnt, int* __restrict__ incl,
                        int* __restrict__ partial, int n) {
    __shared__ int s[256];
    int i = blockIdx.x * 256 + threadIdx.x;
    int v = (i < n) ? cnt[i] : 0;
    s[threadIdx.x] = v;
    __syncthreads();
    for (int off = 1; off < 256; off <<= 1) {
        int t = (threadIdx.x >= (unsigned)off) ? s[threadIdx.x - off] : 0;
        __syncthreads();
        s[threadIdx.x] += t;
        __syncthreads();
    }
    if (i < n) incl[i] = s[threadIdx.x];
    if (threadIdx.x == 255) partial[blockIdx.x] = s[255];
}

// single-block exclusive scan of block partials (nb <= 512)
__global__ void k_scan2(int* __restrict__ partial, int nb) {
    __shared__ int s[512];
    int v = (threadIdx.x < (unsigned)nb) ? partial[threadIdx.x] : 0;
    s[threadIdx.x] = v;
    __syncthreads();
    for (int off = 1; off < 512; off <<= 1) {
        int t = (threadIdx.x >= (unsigned)off) ? s[threadIdx.x - off] : 0;
        __syncthreads();
        s[threadIdx.x] += t;
        __syncthreads();
    }
    if (threadIdx.x < (unsigned)nb) partial[threadIdx.x] = s[threadIdx.x] - v;  // exclusive
}

// row_start / dinv
__global__ void k_scan3(const int* __restrict__ cnt, const int* __restrict__ incl,
                        const int* __restrict__ partial, int* __restrict__ row_start,
                        float* __restrict__ dinv, int n) {
    int i = blockIdx.x * 256 + threadIdx.x;
    if (i < n) {
        row_start[i] = incl[i] - cnt[i] + partial[blockIdx.x];
        dinv[i] = rsqrtf((float)(cnt[i] + 1));  // +1 self-loop
    }
}

// Pass C: LDS cursors (row_start + per-block offset), scatter src into csr (plain stores).
__global__ __launch_bounds__(256) void k_fillh(const int* __restrict__ src,
                                               const int* __restrict__ dst,
                                               const u16* __restrict__ hb,
                                               const int* __restrict__ row_start,
                                               int* __restrict__ csr_src, int e, int n) {
    __shared__ u32 cur[GMAX];
    int g = blockIdx.x & (NG - 1);
    int sub = blockIdx.x >> 3;
    int lo = (int)((long long)n * g / NG);
    int hi = (int)((long long)n * (g + 1) / NG);
    int gsz = hi - lo;
    const u16* bp = hb + (size_t)(g * NSUB + sub) * GMAX;
    for (int j = threadIdx.x; j < gsz; j += 256) cur[j] = (u32)row_start[lo + j] + bp[j];
    __syncthreads();
    long long begin = (long long)e * sub / NSUB;
    long long end   = (long long)e * (sub + 1) / NSUB;
    long long b4 = begin + ((4 - (begin & 3)) & 3);
    if (b4 > end) b4 = end;
    long long e4 = b4 + ((end - b4) & ~3LL);
    for (long long i = begin + threadIdx.x; i < b4; i += 256) {
        int d = dst[i];
        if (d >= lo && d < hi) { u32 pos = atomicAdd(&cur[d - lo], 1u); csr_src[pos] = src[i]; }
    }
    const int4* dp = (const int4*)(dst + b4);
    const int4* sp = (const int4*)(src + b4);
    long long nv = (e4 - b4) >> 2;
    for (long long it = threadIdx.x; it < nv; it += 256) {
        int4 v = dp[it];
        int4 s = sp[it];
        if (v.x >= lo && v.x < hi) { u32 p0 = atomicAdd(&cur[v.x - lo], 1u); csr_src[p0] = s.x; }
        if (v.y >= lo && v.y < hi) { u32 p1 = atomicAdd(&cur[v.y - lo], 1u); csr_src[p1] = s.y; }
        if (v.z >= lo && v.z < hi) { u32 p2 = atomicAdd(&cur[v.z - lo], 1u); csr_src[p2] = s.z; }
        if (v.w >= lo && v.w < hi) { u32 p3 = atomicAdd(&cur[v.w - lo], 1u); csr_src[p3] = s.w; }
    }
    for (long long i = e4 + threadIdx.x; i < end; i += 256) {
        int d = dst[i];
        if (d >= lo && d < hi) { u32 pos = atomicAdd(&cur[d - lo], 1u); csr_src[pos] = src[i]; }
    }
}

// pack pre-scaled source features: xs[i][f] = f16(x[i][f] * dinv[i])
__global__ void k_pack(const float* __restrict__ x, const float* __restrict__ dinv,
                       __half* __restrict__ xs, int n) {
    int t = blockIdx.x * blockDim.x + threadIdx.x;
    int node = t >> 5;
    int f = t & 31;
    if (node >= n || f >= IN_F) return;
    xs[(long long)node * IN_F + f] = __float2half(x[(long long)node * IN_F + f] * dinv[node]);
}

// ---------------- layer 1 aggregation: 16-lane group per node, half2 payload, unroll-8 ----------------
__global__ void k_agg1(const float* __restrict__ x, const __half2* __restrict__ xs2,
                       const float* __restrict__ dinv, const int* __restrict__ row_start,
                       const int* __restrict__ cnt, const int* __restrict__ csr_src,
                       float2* __restrict__ aggX2, int n) {
    int t = blockIdx.x * blockDim.x + threadIdx.x;
    int node = t >> 4;
    int f2 = t & 15;
    if (node >= n || f2 >= 12) return;
    int row = row_start[node];
    int c = cnt[node];
    float ax = 0.0f, ay = 0.0f;
    int j = 0;
    for (; j + 8 <= c; j += 8) {
        const int* cp = csr_src + row + j;
        int s0 = cp[0], s1 = cp[1], s2 = cp[2], s3 = cp[3];
        int s4 = cp[4], s5 = cp[5], s6 = cp[6], s7 = cp[7];
        __half2 h0 = xs2[s0 * 12 + f2];
        __half2 h1 = xs2[s1 * 12 + f2];
        __half2 h2 = xs2[s2 * 12 + f2];
        __half2 h3 = xs2[s3 * 12 + f2];
        __half2 h4 = xs2[s4 * 12 + f2];
        __half2 h5 = xs2[s5 * 12 + f2];
        __half2 h6 = xs2[s6 * 12 + f2];
        __half2 h7 = xs2[s7 * 12 + f2];
        float2 f0 = __half22float2(h0), f1 = __half22float2(h1);
        float2 f2v = __half22float2(h2), f3 = __half22float2(h3);
        float2 f4 = __half22float2(h4), f5 = __half22float2(h5);
        float2 f6 = __half22float2(h6), f7 = __half22float2(h7);
        ax += (f0.x + f1.x) + (f2v.x + f3.x) + ((f4.x + f5.x) + (f6.x + f7.x));
        ay += (f0.y + f1.y) + (f2v.y + f3.y) + ((f4.y + f5.y) + (f6.y + f7.y));
    }
    for (; j < c; ++j) {
        int s = csr_src[row + j];
        float2 fv = __half22float2(xs2[s * 12 + f2]);
        ax += fv.x;
        ay += fv.y;
    }
    float dn = dinv[node];
    float sx = x[(long long)node * IN_F + 2 * f2];
    float sy = x[(long long)node * IN_F + 2 * f2 + 1];
    float2 outv;
    outv.x = (ax + sx * dn) * dn;
    outv.y = (ay + sy * dn) * dn;
    aggX2[(long long)node * 12 + f2] = outv;
}

// ---------------- fused: h1 = relu(aggX@W1+b1); zs = (h1 . W2) * dinv ----------------
__global__ void k_hidden_z(const float* __restrict__ aggX, const float* __restrict__ W1,
                           const float* __restrict__ b1, const float* __restrict__ W2,
                           const float* __restrict__ dinv, float* __restrict__ zs, int n) {
    __shared__ float w[IN_F * HID];
    __shared__ float w2s[HID];
    __shared__ float b1s[HID];
    for (int j = threadIdx.x; j < IN_F * HID; j += blockDim.x) w[j] = W1[j];
    if (threadIdx.x < HID) { w2s[threadIdx.x] = W2[threadIdx.x]; b1s[threadIdx.x] = b1[threadIdx.x]; }
    __syncthreads();
    int t = blockIdx.x * blockDim.x + threadIdx.x;
    int node = t >> 6;
    int f = t & 63;
    if (node >= n) return;
    const float* xr = aggX + (long long)node * IN_F;
    float acc = b1s[f];
#pragma unroll
    for (int k = 0; k < IN_F; ++k) acc += xr[k] * w[k * HID + f];
    float v = fmaxf(acc, 0.0f) * w2s[f];
#pragma unroll
    for (int off = 32; off > 0; off >>= 1) v += __shfl_down(v, off);
    if (f == 0) zs[node] = v * dinv[node];
}

// ---------------- layer 2 gather ----------------
__global__ void k_out(const float* __restrict__ zs, const float* __restrict__ dinv,
                      const int* __restrict__ row_start, const int* __restrict__ cnt,
                      const int* __restrict__ csr_src, const float* __restrict__ b2,
                      float* __restrict__ out, int n) {
    int t = blockIdx.x * blockDim.x + threadIdx.x;
    int node = t >> 6;
    int lane = t & 63;
    if (node >= n) return;
    int row = row_start[node];
    int c = cnt[node];
    float v = 0.0f;
    for (int j = lane; j < c; j += 64) {
        v += zs[csr_src[row + j]];
    }
#pragma unroll
    for (int off = 32; off > 0; off >>= 1) v += __shfl_down(v, off);
    if (lane == 0) {
        out[node] = b2[0] + dinv[node] * (zs[node] + v);
    }
}

extern "C" void kernel_launch(void* const* d_in, const int* in_sizes, int n_in,
                              void* d_out, int out_size, void* d_ws, size_t ws_size,
                              hipStream_t stream) {
    const float* x   = (const float*)d_in[0];
    const int*   ei  = (const int*)d_in[1];
    const float* W1  = (const float*)d_in[2];
    const float* b1  = (const float*)d_in[3];
    const float* W2  = (const float*)d_in[4];
    const float* b2  = (const float*)d_in[5];
    float* out = (float*)d_out;

    const int n = in_sizes[0] / IN_F;      // 100000
    const int e = in_sizes[1] / 2;         // 3200000
    const int* src = ei;
    const int* dst = ei + e;

    const int B = 256;
    const int nb = (n + B - 1) / B;        // 391 <= 512

    // workspace layout (ints first, then u16 hist, then floats/halves)
    int* cnt       = (int*)d_ws;
    int* incl      = cnt + n;
    int* partial   = incl + n;             // 512 entries
    int* row_start = partial + 512;
    int* csr_src   = row_start + n;        // e entries
    u16* hb        = (u16*)(csr_src + e);  // NG*NSUB*GMAX u16 (~12.8 MB)
    float* dinv    = (float*)(hb + (size_t)NG * NSUB * GMAX);
    float* aggX    = dinv + n;             // n*24
    float* zs      = aggX + (size_t)n * IN_F;
    __half* xs     = (__half*)(zs + n);    // n*24 halves

    // CSR build (no device-scope atomics)
    k_hist<<<NG * NSUB, B, 0, stream>>>(dst, hb, e, n);
    k_boff<<<nb, B, 0, stream>>>(hb, cnt, n);
    k_scan1<<<nb, B, 0, stream>>>(cnt, incl, partial, n);
    k_scan2<<<1, 512, 0, stream>>>(partial, nb);
    k_scan3<<<nb, B, 0, stream>>>(cnt, incl, partial, row_start, dinv, n);
    k_fillh<<<NG * NSUB, B, 0, stream>>>(src, dst, hb, row_start, csr_src, e, n);

    // pack pre-scaled f16 features (needs dinv)
    const long long n32 = (long long)n * 32;
    k_pack<<<(int)((n32 + B - 1) / B), B, 0, stream>>>(x, dinv, xs, n);

    // layer 1: gather-aggregate xs (16 lanes/node), then fused transform + zs
    const long long n16 = (long long)n * 16;
    k_agg1<<<(int)((n16 + B - 1) / B), B, 0, stream>>>(x, (const __half2*)xs, dinv,
                                                      row_start, cnt, csr_src,
                                                      (float2*)aggX, n);
    const long long n64 = (long long)n * 64;
    k_hidden_z<<<(int)((n64 + B - 1) / B), B, 0, stream>>>(aggX, W1, b1, W2, dinv, zs, n);

    // layer 2: gather zs
    k_out<<<(int)((n64 + B - 1) / B), B, 0, stream>>>(zs, dinv, row_start, cnt, csr_src, b2, out, n);
}